// Round 3
// baseline (907.958 us; speedup 1.0000x reference)
//
#include <hip/hip_runtime.h>
#include <cstdint>
#include <cstddef>

// Match numpy/XLA float32 semantics: no FMA contraction anywhere.
#pragma clang fp contract(off)

#define KCLS 9
#define PRE_N 6000
#define POST_N 300
#define POOL_N 8192
#define NMS_IOU_T 0.7f
#define NMS_BLOCK 512
#define PER 12   // boxes per thread: 512*12 = 6144 >= 6000
#define TK_BLOCK 1024
#define IDX_INF 0x7FFFFFFF

// ---------------- stage 1: softmax over K=9 ----------------
__global__ void softmax_kernel(const float* __restrict__ labels,
                               float* __restrict__ scores, int ngroups) {
    int g = blockIdx.x * blockDim.x + threadIdx.x;
    if (g >= ngroups) return;
    const float* x = labels + (size_t)g * KCLS;
    float v[KCLS];
    float m = -1e30f;
    #pragma unroll
    for (int k = 0; k < KCLS; ++k) { v[k] = x[k]; m = fmaxf(m, v[k]); }
    float e[KCLS];
    float s = 0.f;
    #pragma unroll
    for (int k = 0; k < KCLS; ++k) { e[k] = expf(v[k] - m); s += e[k]; }
    float* o = scores + (size_t)g * KCLS;
    #pragma unroll
    for (int k = 0; k < KCLS; ++k) o[k] = e[k] / s;
}

// ---------------- stage 2 (fused): 3-pass radix select + pool + bitonic sort + decode ----------------
// One block per image. Replaces 8 dispatches (hist x3, pick x3, sort) + global hist traffic.
__global__ void __launch_bounds__(TK_BLOCK)
topk_kernel(const float* __restrict__ scores,
            const float* __restrict__ deltas,   // [B][A][4]
            const float* __restrict__ anchors,  // [A][4]
            float* __restrict__ pre_boxes,      // [B][6000][4]
            float* __restrict__ pre_scores,     // [B][6000]
            int A) {
    extern __shared__ unsigned long long pool[];  // POOL_N entries = 64 KB (dynamic)
    __shared__ unsigned int hist[2048];
    __shared__ unsigned int ssum[TK_BLOCK];
    __shared__ unsigned int sPrefix, sKrem, cnt;

    const int img = blockIdx.x;
    const int tid = threadIdx.x;
    const int lane = tid & 63;
    const float* sc = scores + (size_t)img * A;

    if (tid == 0) { sPrefix = 0u; sKrem = (unsigned)PRE_N; cnt = 0u; }
    for (int i = tid; i < POOL_N; i += TK_BLOCK) pool[i] = ~0ull;

    // three radix passes over the positive-float bit pattern (uint order == float order)
    const int shifts[3]       = {21, 10, 0};
    const int binsArr[3]      = {2048, 2048, 1024};
    const unsigned pmasks[3]  = {0u, 0xFFE00000u, 0xFFFFFC00u};

    for (int pass = 0; pass < 3; ++pass) {
        const int shift = shifts[pass];
        const int bins = binsArr[pass];
        const unsigned pmask = pmasks[pass];
        for (int i = tid; i < bins; i += TK_BLOCK) hist[i] = 0u;
        __syncthreads();                        // hist zeroed; sPrefix/sKrem from prev pass visible
        const unsigned prefix = sPrefix & pmask;  // == sPrefix (lower bits never set yet)
        for (int i = tid; i < A; i += TK_BLOCK) {
            unsigned v = __float_as_uint(sc[i]);
            if ((v & pmask) == prefix)
                atomicAdd(&hist[(v >> shift) & (unsigned)(bins - 1)], 1u);
        }
        __syncthreads();
        // block-wide inclusive suffix scan of per-thread chunk sums
        const int per = bins / TK_BLOCK;        // 2, 2, 1
        unsigned my = 0;
        for (int i = 0; i < per; ++i) my += hist[tid * per + i];
        ssum[tid] = my;
        __syncthreads();
        for (int d = 1; d < TK_BLOCK; d <<= 1) {
            unsigned v = (tid + d < TK_BLOCK) ? ssum[tid + d] : 0u;
            __syncthreads();
            ssum[tid] += v;
            __syncthreads();
        }
        const unsigned krem = sKrem;            // all threads read BEFORE the unique writer updates
        const unsigned above = ssum[tid] - my;  // count in strictly-higher chunks
        __syncthreads();                        // reads of sKrem done
        if (above < krem && above + my >= krem) {   // exactly one thread
            unsigned cum = above;
            for (int b = per - 1; b >= 0; --b) {
                unsigned c = hist[tid * per + b];
                if (cum + c >= krem) {
                    sPrefix = prefix | ((unsigned)(tid * per + b) << shift);
                    sKrem = krem - cum;
                    break;
                }
                cum += c;
            }
        }
        __syncthreads();                        // writer's update visible
    }

    const unsigned T = sPrefix;  // exact bits of the 6000th-largest score

    // wave-aggregated push of all scores >= T (count(>T) <= 5999, ties included)
    for (int i = tid; i < A; i += TK_BLOCK) {   // A % 1024 == 0: no tail divergence
        unsigned v = __float_as_uint(sc[i]);
        bool push = (v >= T);
        unsigned long long bal = __ballot(push ? 1 : 0);
        if (push) {
            int leader = __ffsll(bal) - 1;
            int rank = __popcll(bal & ((1ull << lane) - 1ull));
            unsigned base = 0;
            if (lane == leader)
                base = atomicAdd(&cnt, (unsigned)__popcll(bal));
            base = (unsigned)__shfl((int)base, leader);
            unsigned pos = base + (unsigned)rank;
            if (pos < POOL_N)
                pool[pos] = (((unsigned long long)(~v)) << 32) | (unsigned long long)(unsigned)i;
        }
    }
    __syncthreads();

    // bitonic sort ascending: key = (~score_bits, index) -> score desc, index asc (top_k tie order)
    for (int k = 2; k <= POOL_N; k <<= 1) {
        for (int j = k >> 1; j > 0; j >>= 1) {
            #pragma unroll
            for (int s = 0; s < POOL_N / TK_BLOCK; ++s) {
                int i = tid + s * TK_BLOCK;
                int ixj = i ^ j;
                if (ixj > i) {
                    unsigned long long a = pool[i], b = pool[ixj];
                    bool up = ((i & k) == 0);
                    if ((a > b) == up) { pool[i] = b; pool[ixj] = a; }
                }
            }
            __syncthreads();
        }
    }

    // decode boxes for the top-6000 (reference float32 op order, no contraction)
    for (int r = tid; r < PRE_N; r += TK_BLOCK) {
        unsigned long long key = pool[r];
        unsigned idx = (unsigned)(key & 0xFFFFFFFFull);
        unsigned sbits = ~((unsigned)(key >> 32));
        float score = __uint_as_float(sbits);
        float a0 = anchors[(size_t)idx * 4 + 0];
        float a1 = anchors[(size_t)idx * 4 + 1];
        float a2 = anchors[(size_t)idx * 4 + 2];
        float a3 = anchors[(size_t)idx * 4 + 3];
        const float* dd = deltas + ((size_t)img * A + idx) * 4;
        float d0 = dd[0] * 0.1f;
        float d1 = dd[1] * 0.1f;
        float d2 = dd[2] * 0.2f;
        float d3 = dd[3] * 0.2f;
        float anc_w = a3 - a1;
        float anc_h = a2 - a0;
        float anc_cx = a1 + 0.5f * anc_w;
        float anc_cy = a0 + 0.5f * anc_h;
        float bb_w = expf(d3) * anc_w;
        float bb_h = expf(d2) * anc_h;
        float bb_cx = d1 * anc_w + anc_cx;
        float bb_cy = d0 * anc_h + anc_cy;
        float y1 = bb_cy - 0.5f * bb_h;
        float x1 = bb_cx - 0.5f * bb_w;
        float y2 = bb_h + y1;
        float x2 = bb_w + x1;
        float* ob = pre_boxes + ((size_t)img * PRE_N + r) * 4;
        ob[0] = y1; ob[1] = x1; ob[2] = y2; ob[3] = x2;
        pre_scores[(size_t)img * PRE_N + r] = score;
    }
}

// ---------------- stage 3: greedy NMS (scores sorted => argmax == first alive) ----------------
// __launch_bounds__(512, 2): 256-VGPR budget so the 6x12 per-thread box arrays stay in
// registers (round-2 profile: VGPR_Count=48, FETCH_SIZE=1586 MB => scratch spill reloaded
// every iteration). Pivot propagated via owner-write to double-buffered LDS (no dependent
// global read per iteration). 2 barriers/iter.
__global__ void __launch_bounds__(NMS_BLOCK, 2)
nms_kernel(const float* __restrict__ pre_boxes,
           const float* __restrict__ pre_scores,
           float* __restrict__ out_boxes,    // [B][300][4]
           float* __restrict__ out_scores) { // [B][300]
    const int img = blockIdx.x;
    const int tid = threadIdx.x;
    const int lane = tid & 63;
    const float4* bb4 = (const float4*)(pre_boxes + (size_t)img * PRE_N * 4);
    const float* psc = pre_scores + (size_t)img * PRE_N;
    float* ob_base = out_boxes + (size_t)img * POST_N * 4;
    float* os_base = out_scores + (size_t)img * POST_N;

    // pre-zero this image's output (replaces host-side memset; rows past the last
    // valid pick must be zero per reference's valid-flag masking)
    for (int i = tid; i < POST_N * 4; i += NMS_BLOCK) ob_base[i] = 0.f;
    for (int i = tid; i < POST_N; i += NMS_BLOCK) os_base[i] = 0.f;

    float by1[PER], bx1[PER], by2[PER], bx2[PER], bar[PER], bsc[PER];
    unsigned alive = 0u;
    #pragma unroll
    for (int s = 0; s < PER; ++s) {
        int j = tid + s * NMS_BLOCK;
        if (j < PRE_N) {
            float4 b4 = bb4[j];
            by1[s] = b4.x; bx1[s] = b4.y; by2[s] = b4.z; bx2[s] = b4.w;
            bar[s] = (b4.z - b4.x) * (b4.w - b4.y);
            bsc[s] = psc[j];
            alive |= (1u << s);
        } else {
            by1[s] = bx1[s] = by2[s] = bx2[s] = bar[s] = bsc[s] = 0.f;
        }
    }

    __shared__ int slot[2];
    __shared__ float sPiv[2][6];
    if (tid == 0) { slot[0] = IDX_INF; slot[1] = IDX_INF; }
    __syncthreads();

    for (int it = 0; it < POST_N; ++it) {
        const int c = it & 1;
        // first alive index owned by this thread (j = tid + s*NMS_BLOCK increases with s)
        int lm = alive ? (tid + (__ffs(alive) - 1) * NMS_BLOCK) : IDX_INF;
        #pragma unroll
        for (int off = 32; off > 0; off >>= 1)
            lm = min(lm, __shfl_down(lm, off));
        if (lane == 0 && lm != IDX_INF) atomicMin(&slot[c], lm);
        if (tid == 0) slot[c ^ 1] = IDX_INF;   // idle slot this window: race-free
        __syncthreads();                       // (A) mins posted
        int p = slot[c];
        if (p == IDX_INF) break;               // uniform: all suppressed; rest stays zero

        if (tid == (p & (NMS_BLOCK - 1))) {    // owner publishes pivot + emits output row
            int sd = p / NMS_BLOCK;
            float py1 = 0.f, px1 = 0.f, py2 = 0.f, px2 = 0.f, pa = 0.f, pscr = 0.f;
            #pragma unroll
            for (int s = 0; s < PER; ++s)
                if (s == sd) { py1 = by1[s]; px1 = bx1[s]; py2 = by2[s]; px2 = bx2[s]; pa = bar[s]; pscr = bsc[s]; }
            sPiv[c][0] = py1; sPiv[c][1] = px1; sPiv[c][2] = py2;
            sPiv[c][3] = px2; sPiv[c][4] = pa;  sPiv[c][5] = pscr;
            float* ob = ob_base + it * 4;
            ob[0] = py1; ob[1] = px1; ob[2] = py2; ob[3] = px2;
            os_base[it] = pscr;
        }
        __syncthreads();                       // (B) pivot visible
        float py1 = sPiv[c][0], px1 = sPiv[c][1], py2 = sPiv[c][2];
        float px2 = sPiv[c][3], pa = sPiv[c][4];
        #pragma unroll
        for (int s = 0; s < PER; ++s) {
            float iy1 = fmaxf(py1, by1[s]);
            float ix1 = fmaxf(px1, bx1[s]);
            float iy2 = fminf(py2, by2[s]);
            float ix2 = fminf(px2, bx2[s]);
            float ih = iy2 - iy1; ih = ih > 0.f ? ih : 0.f;
            float iw = ix2 - ix1; iw = iw > 0.f ? iw : 0.f;
            float inter = ih * iw;
            float den = bar[s] + pa - inter + 1e-9f;   // ref order: ((areas+b_area)-inter)+eps
            float hi = 0.7000007f * den;               // decisive-suppress bound
            float lo = 0.6999993f * den;               // decisive-keep bound
            bool sup = inter > hi;
            if (inter >= lo && inter <= hi)            // borderline: exact reference path
                sup = (inter / den) > NMS_IOU_T;
            if (sup) alive &= ~(1u << s);
        }
    }
}

extern "C" void kernel_launch(void* const* d_in, const int* in_sizes, int n_in,
                              void* d_out, int out_size, void* d_ws, size_t ws_size,
                              hipStream_t stream) {
    const float* deltas  = (const float*)d_in[0];  // (B, A, 4)
    const float* labels  = (const float*)d_in[1];  // (B, FH, FW, 9)
    const float* anchors = (const float*)d_in[2];  // (A, 4)
    float* out = (float*)d_out;

    const int A = in_sizes[2] / 4;                 // 147456
    const int B = in_sizes[0] / (A * 4);           // 32
    const int ngroups = in_sizes[1] / KCLS;        // B*FH*FW

    // workspace layout
    float* scores     = (float*)d_ws;                                // B*A
    float* pre_boxes  = scores + (size_t)B * A;                      // B*6000*4
    float* pre_scores = pre_boxes + (size_t)B * PRE_N * 4;           // B*6000

    float* out_boxes  = out;                        // B*300*4
    float* out_scores = out + (size_t)B * POST_N * 4;

    softmax_kernel<<<(ngroups + 255) / 256, 256, 0, stream>>>(labels, scores, ngroups);

    topk_kernel<<<B, TK_BLOCK, POOL_N * sizeof(unsigned long long), stream>>>(
        scores, deltas, anchors, pre_boxes, pre_scores, A);

    nms_kernel<<<B, NMS_BLOCK, 0, stream>>>(pre_boxes, pre_scores, out_boxes, out_scores);
}